// Round 1
// baseline (946.003 us; speedup 1.0000x reference)
//
#include <hip/hip_runtime.h>
#include <hip/hip_bf16.h>
#include <math.h>

#define LEAKY 0.01f

__global__ void zero_i32(int* __restrict__ p, int n) {
    int i = blockIdx.x * blockDim.x + threadIdx.x;
    if (i < n) p[i] = 0;
}

__global__ void count_edges(const int* __restrict__ row, int E, int* __restrict__ deg) {
    int i = blockIdx.x * blockDim.x + threadIdx.x;
    if (i < E) atomicAdd(&deg[row[i]], 1);
}

// Single-block chunked exclusive scan: deg[N] -> row_ptr[N+1]
__global__ __launch_bounds__(1024) void scan_deg(const int* __restrict__ deg,
                                                 int* __restrict__ row_ptr, int N) {
    __shared__ int sums[1024];
    int t = threadIdx.x;
    int C = (N + 1023) >> 10;
    int s = t * C;
    int e = s + C;
    if (s > N) s = N;
    if (e > N) e = N;
    int local = 0;
    for (int i = s; i < e; i++) local += deg[i];
    sums[t] = local;
    __syncthreads();
    // Hillis-Steele inclusive scan
    for (int off = 1; off < 1024; off <<= 1) {
        int v = (t >= off) ? sums[t - off] : 0;
        __syncthreads();
        sums[t] += v;
        __syncthreads();
    }
    int run = (t == 0) ? 0 : sums[t - 1];
    for (int i = s; i < e; i++) { row_ptr[i] = run; run += deg[i]; }
    if (t == 1023) row_ptr[N] = sums[1023];
}

__global__ void copy_i32(const int* __restrict__ a, int* __restrict__ b, int n) {
    int i = blockIdx.x * blockDim.x + threadIdx.x;
    if (i < n) b[i] = a[i];
}

__global__ void fill_csr(const int* __restrict__ row, const int* __restrict__ col,
                         const float* __restrict__ val, int E,
                         int* __restrict__ cursor, int* __restrict__ csr_col,
                         float* __restrict__ csr_val) {
    int i = blockIdx.x * blockDim.x + threadIdx.x;
    if (i < E) {
        int r = row[i];
        int p = atomicAdd(&cursor[r], 1);
        csr_col[p] = col[i];
        csr_val[p] = val[i];
    }
}

// Layer 0: feats = concat(user_embed, entity_embed); d_in=64, d_out=64.
// One wave per node, lane = dim. Fused: neighbor aggregate (CSR gather) ->
// bilinear MLP -> leaky_relu -> L2 normalize.
__global__ __launch_bounds__(256) void layer0(
    const float* __restrict__ ue, const float* __restrict__ ee,
    const int* __restrict__ row_ptr, const int* __restrict__ csr_col,
    const float* __restrict__ csr_val,
    const float* __restrict__ W1, const float* __restrict__ b1,
    const float* __restrict__ W2, const float* __restrict__ b2,
    float* __restrict__ out, int N, int NU) {
    // W1,W2 interleaved: w12[k*128 + d*2 + {0,1}] = {W1[k][d], W2[k][d]}
    __shared__ __align__(16) float w12[64 * 64 * 2];
    __shared__ __align__(16) float sst[4 * 64 * 2];
    for (int idx = threadIdx.x; idx < 4096; idx += 256) {
        int k = idx >> 6, d = idx & 63;
        w12[k * 128 + d * 2]     = W1[idx];
        w12[k * 128 + d * 2 + 1] = W2[idx];
    }
    __syncthreads();
    int wave = threadIdx.x >> 6, lane = threadIdx.x & 63;
    int node = blockIdx.x * 4 + wave;
    if (node >= N) return;
    const float* xp = (node < NU) ? (ue + (size_t)node * 64)
                                  : (ee + (size_t)(node - NU) * 64);
    float x = xp[lane];
    float acc = 0.f;
    int e0 = row_ptr[node], e1 = row_ptr[node + 1];
    for (int e = e0; e < e1; e++) {
        int c = csr_col[e];
        float v = csr_val[e];
        const float* f = (c < NU) ? (ue + (size_t)c * 64)
                                  : (ee + (size_t)(c - NU) * 64);
        acc = fmaf(v, f[lane], acc);
    }
    float* sp = &sst[wave * 128];
    sp[lane * 2]     = x + acc;   // s1
    sp[lane * 2 + 1] = x * acc;   // s2
    __threadfence_block();        // order intra-wave LDS write -> cross-lane read
    float o = b1[lane] + b2[lane];
#pragma unroll 8
    for (int k = 0; k < 64; k++) {
        float2 s = *(const float2*)&sp[k * 2];              // broadcast read
        float2 w = *(const float2*)&w12[k * 128 + lane * 2]; // stride-1, conflict-free
        o = fmaf(s.x, w.x, o);
        o = fmaf(s.y, w.y, o);
    }
    float h = (o > 0.f) ? o : LEAKY * o;
    float ss = h * h;
#pragma unroll
    for (int m = 32; m >= 1; m >>= 1) ss += __shfl_xor(ss, m, 64);
    float scale = 1.0f / fmaxf(sqrtf(ss), 1e-12f);
    out[(size_t)node * 64 + lane] = h * scale;
}

// Layer 1: feats = a1 (N x 64), d_out = 32. Lanes 0-31 carry outputs.
__global__ __launch_bounds__(256) void layer1(
    const float* __restrict__ feats,
    const int* __restrict__ row_ptr, const int* __restrict__ csr_col,
    const float* __restrict__ csr_val,
    const float* __restrict__ W1, const float* __restrict__ b1,
    const float* __restrict__ W2, const float* __restrict__ b2,
    float* __restrict__ out, int N) {
    __shared__ __align__(16) float w12[64 * 32 * 2];
    __shared__ __align__(16) float sst[4 * 64 * 2];
    for (int idx = threadIdx.x; idx < 2048; idx += 256) {
        int k = idx >> 5, d = idx & 31;
        w12[k * 64 + d * 2]     = W1[idx];
        w12[k * 64 + d * 2 + 1] = W2[idx];
    }
    __syncthreads();
    int wave = threadIdx.x >> 6, lane = threadIdx.x & 63;
    int node = blockIdx.x * 4 + wave;
    if (node >= N) return;
    float x = feats[(size_t)node * 64 + lane];
    float acc = 0.f;
    int e0 = row_ptr[node], e1 = row_ptr[node + 1];
    for (int e = e0; e < e1; e++) {
        int c = csr_col[e];
        float v = csr_val[e];
        acc = fmaf(v, feats[(size_t)c * 64 + lane], acc);
    }
    float* sp = &sst[wave * 128];
    sp[lane * 2]     = x + acc;
    sp[lane * 2 + 1] = x * acc;
    __threadfence_block();
    int d = lane & 31;  // lanes 32-63 compute duplicates, discarded
    float o = b1[d] + b2[d];
#pragma unroll 8
    for (int k = 0; k < 64; k++) {
        float2 s = *(const float2*)&sp[k * 2];
        float2 w = *(const float2*)&w12[k * 64 + d * 2];
        o = fmaf(s.x, w.x, o);
        o = fmaf(s.y, w.y, o);
    }
    float h = (o > 0.f) ? o : LEAKY * o;
    float hh = (lane < 32) ? h : 0.f;
    float ss = hh * hh;
#pragma unroll
    for (int m = 32; m >= 1; m >>= 1) ss += __shfl_xor(ss, m, 64);
    float scale = 1.0f / fmaxf(sqrtf(ss), 1e-12f);
    if (lane < 32) out[(size_t)node * 32 + lane] = h * scale;
}

// final = concat(a0, a1, a2); score[b] = dot(final[u], final[NU+i]) over 160 dims
__global__ __launch_bounds__(256) void score_pairs(
    const float* __restrict__ ue, const float* __restrict__ ee,
    const float* __restrict__ a1, const float* __restrict__ a2,
    const int* __restrict__ uid, const int* __restrict__ iid,
    float* __restrict__ out, int B, int NU) {
    int wave = threadIdx.x >> 6, lane = threadIdx.x & 63;
    int p = blockIdx.x * 4 + wave;
    if (p >= B) return;
    int u = uid[p], it = iid[p];
    size_t un = (size_t)u, in = (size_t)(NU + it);
    float s = ue[(size_t)u * 64 + lane] * ee[(size_t)it * 64 + lane];
    s = fmaf(a1[un * 64 + lane], a1[in * 64 + lane], s);
    if (lane < 32) s = fmaf(a2[un * 32 + lane], a2[in * 32 + lane], s);
#pragma unroll
    for (int m = 32; m >= 1; m >>= 1) s += __shfl_xor(s, m, 64);
    if (lane == 0) out[p] = s;
}

extern "C" void kernel_launch(void* const* d_in, const int* in_sizes, int n_in,
                              void* d_out, int out_size, void* d_ws, size_t ws_size,
                              hipStream_t stream) {
    const int*   edge_row  = (const int*)d_in[0];
    const int*   edge_col  = (const int*)d_in[1];
    const float* edge_vals = (const float*)d_in[2];
    const float* ue        = (const float*)d_in[3];
    const float* ee        = (const float*)d_in[4];
    const float* W1_0 = (const float*)d_in[5];
    const float* b1_0 = (const float*)d_in[6];
    const float* W2_0 = (const float*)d_in[7];
    const float* b2_0 = (const float*)d_in[8];
    const float* W1_1 = (const float*)d_in[9];
    const float* b1_1 = (const float*)d_in[10];
    const float* W2_1 = (const float*)d_in[11];
    const float* b2_1 = (const float*)d_in[12];
    const int*   uid  = (const int*)d_in[13];
    const int*   iid  = (const int*)d_in[14];
    float* out = (float*)d_out;

    const int E  = in_sizes[0];
    const int NU = in_sizes[3] / 64;
    const int NE = in_sizes[4] / 64;
    const int N  = NU + NE;
    const int B  = in_sizes[13];

    char* ws = (char*)d_ws;
    size_t off = 0;
    auto alloc = [&](size_t bytes) -> char* {
        char* p = ws + off;
        off = (off + bytes + 255) & ~(size_t)255;
        return p;
    };
    int*   deg     = (int*)alloc((size_t)N * 4);
    int*   row_ptr = (int*)alloc((size_t)(N + 1) * 4);
    int*   cursor  = (int*)alloc((size_t)N * 4);
    int*   csr_col = (int*)alloc((size_t)E * 4);
    float* csr_val = (float*)alloc((size_t)E * 4);
    float* a1      = (float*)alloc((size_t)N * 64 * 4);
    float* a2      = (float*)alloc((size_t)N * 32 * 4);
    (void)ws_size; (void)n_in; (void)out_size; (void)NE;

    zero_i32<<<(N + 255) / 256, 256, 0, stream>>>(deg, N);
    count_edges<<<(E + 255) / 256, 256, 0, stream>>>(edge_row, E, deg);
    scan_deg<<<1, 1024, 0, stream>>>(deg, row_ptr, N);
    copy_i32<<<(N + 255) / 256, 256, 0, stream>>>(row_ptr, cursor, N);
    fill_csr<<<(E + 255) / 256, 256, 0, stream>>>(edge_row, edge_col, edge_vals, E,
                                                  cursor, csr_col, csr_val);
    layer0<<<(N + 3) / 4, 256, 0, stream>>>(ue, ee, row_ptr, csr_col, csr_val,
                                            W1_0, b1_0, W2_0, b2_0, a1, N, NU);
    layer1<<<(N + 3) / 4, 256, 0, stream>>>(a1, row_ptr, csr_col, csr_val,
                                            W1_1, b1_1, W2_1, b2_1, a2, N);
    score_pairs<<<(B + 3) / 4, 256, 0, stream>>>(ue, ee, a1, a2, uid, iid, out, B, NU);
}

// Round 2
// 677.877 us; speedup vs baseline: 1.3955x; 1.3955x over previous
//
#include <hip/hip_runtime.h>
#include <hip/hip_bf16.h>
#include <math.h>

#define LEAKY 0.01f

__global__ void zero_i32(int* __restrict__ p, int n) {
    int i = blockIdx.x * blockDim.x + threadIdx.x;
    if (i < n) p[i] = 0;
}

__global__ void count_edges(const int* __restrict__ row, int E, int* __restrict__ deg) {
    int i = blockIdx.x * blockDim.x + threadIdx.x;
    if (i < E) atomicAdd(&deg[row[i]], 1);
}

// Single-block chunked exclusive scan: deg[N] -> row_ptr[N+1]
__global__ __launch_bounds__(1024) void scan_deg(const int* __restrict__ deg,
                                                 int* __restrict__ row_ptr, int N) {
    __shared__ int sums[1024];
    int t = threadIdx.x;
    int C = (N + 1023) >> 10;
    int s = t * C;
    int e = s + C;
    if (s > N) s = N;
    if (e > N) e = N;
    int local = 0;
    for (int i = s; i < e; i++) local += deg[i];
    sums[t] = local;
    __syncthreads();
    for (int off = 1; off < 1024; off <<= 1) {
        int v = (t >= off) ? sums[t - off] : 0;
        __syncthreads();
        sums[t] += v;
        __syncthreads();
    }
    int run = (t == 0) ? 0 : sums[t - 1];
    for (int i = s; i < e; i++) { row_ptr[i] = run; run += deg[i]; }
    if (t == 1023) row_ptr[N] = sums[1023];
}

__global__ void copy_i32(const int* __restrict__ a, int* __restrict__ b, int n) {
    int i = blockIdx.x * blockDim.x + threadIdx.x;
    if (i < n) b[i] = a[i];
}

// a0 = concat(user_embed, entity_embed), contiguous N x 64
__global__ void build_a0(const float4* __restrict__ ue, const float4* __restrict__ ee,
                         float4* __restrict__ a0, int nu4, int ntot4) {
    int i = blockIdx.x * blockDim.x + threadIdx.x;
    if (i < ntot4) a0[i] = (i < nu4) ? ue[i] : ee[i - nu4];
}

// CSR packed as int2 {col, float_bits(val)} -> one 8B load per edge
__global__ void fill_csr(const int* __restrict__ row, const int* __restrict__ col,
                         const float* __restrict__ val, int E,
                         int* __restrict__ cursor, int2* __restrict__ csr) {
    int i = blockIdx.x * blockDim.x + threadIdx.x;
    if (i < E) {
        int r = row[i];
        int p = atomicAdd(&cursor[r], 1);
        csr[p] = make_int2(col[i], __float_as_int(val[i]));
    }
}

// Fused GNN layer: one wave per node (lane = dim). CSR gather-aggregate ->
// bilinear MLP -> leaky_relu -> L2 normalize.
// Weights transposed in LDS with stride 68 (4-word-aligned, groups of 8 lanes
// tile all 32 banks -> conflict-free ds_read_b128). s1/s2 interleaved in LDS,
// read as same-address float4 broadcasts (free).
template<int DOUT>
__global__ __launch_bounds__(512) void gnn_layer(
    const float* __restrict__ feats, const int2* __restrict__ csr,
    const int* __restrict__ row_ptr,
    const float* __restrict__ W1, const float* __restrict__ b1,
    const float* __restrict__ W2, const float* __restrict__ b2,
    float* __restrict__ out, int N) {
    __shared__ __align__(16) float w1t[DOUT * 68];
    __shared__ __align__(16) float w2t[DOUT * 68];
    __shared__ __align__(16) float s12[8][128];
    for (int idx = threadIdx.x; idx < 64 * DOUT; idx += 512) {
        int k = idx / DOUT, d = idx % DOUT;   // W[k][d], k-major in global
        w1t[d * 68 + k] = W1[idx];
        w2t[d * 68 + k] = W2[idx];
    }
    __syncthreads();
    int wv = threadIdx.x >> 6, lane = threadIdx.x & 63;
    int node = blockIdx.x * 8 + wv;
    if (node >= N) return;
    float x = feats[(size_t)node * 64 + lane];
    int e0 = row_ptr[node], e1 = row_ptr[node + 1];
    float acc = 0.f;
    int e = e0;
    // unrolled by 4: independent gather addresses -> loads pipeline in vmcnt queue
    for (; e + 4 <= e1; e += 4) {
        int2 p0 = csr[e], p1 = csr[e + 1], p2 = csr[e + 2], p3 = csr[e + 3];
        float f0 = feats[(size_t)p0.x * 64 + lane];
        float f1 = feats[(size_t)p1.x * 64 + lane];
        float f2 = feats[(size_t)p2.x * 64 + lane];
        float f3 = feats[(size_t)p3.x * 64 + lane];
        acc = fmaf(__int_as_float(p0.y), f0, acc);
        acc = fmaf(__int_as_float(p1.y), f1, acc);
        acc = fmaf(__int_as_float(p2.y), f2, acc);
        acc = fmaf(__int_as_float(p3.y), f3, acc);
    }
    for (; e < e1; e++) {
        int2 p = csr[e];
        acc = fmaf(__int_as_float(p.y), feats[(size_t)p.x * 64 + lane], acc);
    }
    float* sp = s12[wv];
    *(float2*)&sp[lane * 2] = make_float2(x + acc, x * acc);  // s1, s2 interleaved
    __threadfence_block();  // order intra-wave LDS write -> cross-lane read
    int d = lane % DOUT;
    float o = b1[d] + b2[d];
    const float* w1p = &w1t[d * 68];
    const float* w2p = &w2t[d * 68];
#pragma unroll
    for (int k = 0; k < 64; k += 4) {
        float4 sa = *(const float4*)&sp[2 * k];       // s1[k],s2[k],s1[k+1],s2[k+1]
        float4 sb = *(const float4*)&sp[2 * k + 4];   // s1[k+2],s2[k+2],s1[k+3],s2[k+3]
        float4 wa = *(const float4*)&w1p[k];          // w1[k..k+3]
        float4 wb = *(const float4*)&w2p[k];          // w2[k..k+3]
        o = fmaf(sa.x, wa.x, o);
        o = fmaf(sa.y, wb.x, o);
        o = fmaf(sa.z, wa.y, o);
        o = fmaf(sa.w, wb.y, o);
        o = fmaf(sb.x, wa.z, o);
        o = fmaf(sb.y, wb.z, o);
        o = fmaf(sb.z, wa.w, o);
        o = fmaf(sb.w, wb.w, o);
    }
    float h = (o > 0.f) ? o : LEAKY * o;
    float hh = (lane < DOUT) ? h : 0.f;
    float ss = hh * hh;
#pragma unroll
    for (int m = 32; m >= 1; m >>= 1) ss += __shfl_xor(ss, m, 64);
    float scale = 1.0f / fmaxf(sqrtf(ss), 1e-12f);
    if (lane < DOUT) out[(size_t)node * DOUT + lane] = h * scale;
}

// final = concat(a0, a1, a2); score[b] = dot(final[u], final[NU+i]) over 160 dims
__global__ __launch_bounds__(256) void score_pairs(
    const float* __restrict__ a0, const float* __restrict__ a1,
    const float* __restrict__ a2,
    const int* __restrict__ uid, const int* __restrict__ iid,
    float* __restrict__ out, int B, int NU) {
    int wave = threadIdx.x >> 6, lane = threadIdx.x & 63;
    int p = blockIdx.x * 4 + wave;
    if (p >= B) return;
    int u = uid[p], it = iid[p];
    size_t un = (size_t)u, in = (size_t)(NU + it);
    float s = a0[un * 64 + lane] * a0[in * 64 + lane];
    s = fmaf(a1[un * 64 + lane], a1[in * 64 + lane], s);
    if (lane < 32) s = fmaf(a2[un * 32 + lane], a2[in * 32 + lane], s);
#pragma unroll
    for (int m = 32; m >= 1; m >>= 1) s += __shfl_xor(s, m, 64);
    if (lane == 0) out[p] = s;
}

extern "C" void kernel_launch(void* const* d_in, const int* in_sizes, int n_in,
                              void* d_out, int out_size, void* d_ws, size_t ws_size,
                              hipStream_t stream) {
    const int*   edge_row  = (const int*)d_in[0];
    const int*   edge_col  = (const int*)d_in[1];
    const float* edge_vals = (const float*)d_in[2];
    const float* ue        = (const float*)d_in[3];
    const float* ee        = (const float*)d_in[4];
    const float* W1_0 = (const float*)d_in[5];
    const float* b1_0 = (const float*)d_in[6];
    const float* W2_0 = (const float*)d_in[7];
    const float* b2_0 = (const float*)d_in[8];
    const float* W1_1 = (const float*)d_in[9];
    const float* b1_1 = (const float*)d_in[10];
    const float* W2_1 = (const float*)d_in[11];
    const float* b2_1 = (const float*)d_in[12];
    const int*   uid  = (const int*)d_in[13];
    const int*   iid  = (const int*)d_in[14];
    float* out = (float*)d_out;

    const int E  = in_sizes[0];
    const int NU = in_sizes[3] / 64;
    const int NE = in_sizes[4] / 64;
    const int N  = NU + NE;
    const int B  = in_sizes[13];

    char* ws = (char*)d_ws;
    size_t off = 0;
    auto alloc = [&](size_t bytes) -> char* {
        char* p = ws + off;
        off = (off + bytes + 255) & ~(size_t)255;
        return p;
    };
    int*   deg     = (int*)alloc((size_t)N * 4);
    int*   row_ptr = (int*)alloc((size_t)(N + 1) * 4);
    int*   cursor  = (int*)alloc((size_t)N * 4);
    int2*  csr     = (int2*)alloc((size_t)E * 8);
    float* a0      = (float*)alloc((size_t)N * 64 * 4);
    float* a1      = (float*)alloc((size_t)N * 64 * 4);
    float* a2      = (float*)alloc((size_t)N * 32 * 4);
    (void)ws_size; (void)n_in; (void)out_size; (void)NE;

    zero_i32<<<(N + 255) / 256, 256, 0, stream>>>(deg, N);
    count_edges<<<(E + 255) / 256, 256, 0, stream>>>(edge_row, E, deg);
    scan_deg<<<1, 1024, 0, stream>>>(deg, row_ptr, N);
    copy_i32<<<(N + 255) / 256, 256, 0, stream>>>(row_ptr, cursor, N);
    fill_csr<<<(E + 255) / 256, 256, 0, stream>>>(edge_row, edge_col, edge_vals, E,
                                                  cursor, csr);
    int ntot4 = N * 16, nu4 = NU * 16;
    build_a0<<<(ntot4 + 255) / 256, 256, 0, stream>>>((const float4*)ue, (const float4*)ee,
                                                      (float4*)a0, nu4, ntot4);
    gnn_layer<64><<<(N + 7) / 8, 512, 0, stream>>>(a0, csr, row_ptr,
                                                   W1_0, b1_0, W2_0, b2_0, a1, N);
    gnn_layer<32><<<(N + 7) / 8, 512, 0, stream>>>(a1, csr, row_ptr,
                                                   W1_1, b1_1, W2_1, b2_1, a2, N);
    score_pairs<<<(B + 3) / 4, 256, 0, stream>>>(a0, a1, a2, uid, iid, out, B, NU);
}

// Round 3
// 518.352 us; speedup vs baseline: 1.8250x; 1.3078x over previous
//
#include <hip/hip_runtime.h>
#include <hip/hip_bf16.h>
#include <math.h>

#define LEAKY 0.01f
#define SCAN_BLOCK 256
#define SCAN_ITEMS 4
#define SCAN_TILE (SCAN_BLOCK * SCAN_ITEMS)  // 1024 items per block

__global__ void zero_i32(int* __restrict__ p, int n) {
    int i = blockIdx.x * blockDim.x + threadIdx.x;
    if (i < n) p[i] = 0;
}

__global__ void count_edges(const int* __restrict__ row, int E, int* __restrict__ deg) {
    int i = blockIdx.x * blockDim.x + threadIdx.x;
    if (i < E) atomicAdd(&deg[row[i]], 1);
}

// ---- 3-phase device-wide exclusive scan of deg[N] -> row_ptr[N+1], cursor[N] ----
__global__ __launch_bounds__(SCAN_BLOCK) void scan_phase1(
    const int* __restrict__ deg, int* __restrict__ blocksum, int N) {
    __shared__ int red[SCAN_BLOCK];
    int b = blockIdx.x, t = threadIdx.x;
    int base = b * SCAN_TILE + t * SCAN_ITEMS;
    int s = 0;
#pragma unroll
    for (int j = 0; j < SCAN_ITEMS; j++) {
        int i = base + j;
        if (i < N) s += deg[i];
    }
    red[t] = s;
    __syncthreads();
    for (int off = SCAN_BLOCK / 2; off > 0; off >>= 1) {
        if (t < off) red[t] += red[t + off];
        __syncthreads();
    }
    if (t == 0) blocksum[b] = red[0];
}

__global__ __launch_bounds__(1024) void scan_phase2(
    const int* __restrict__ blocksum, int* __restrict__ blockoff,
    int* __restrict__ row_ptr, int G, int N) {
    __shared__ int sums[1024];
    int t = threadIdx.x;
    sums[t] = (t < G) ? blocksum[t] : 0;
    __syncthreads();
    for (int off = 1; off < 1024; off <<= 1) {
        int v = (t >= off) ? sums[t - off] : 0;
        __syncthreads();
        sums[t] += v;
        __syncthreads();
    }
    if (t < G) blockoff[t] = (t == 0) ? 0 : sums[t - 1];
    if (t == G - 1) row_ptr[N] = sums[t];
}

__global__ __launch_bounds__(SCAN_BLOCK) void scan_phase3(
    const int* __restrict__ deg, const int* __restrict__ blockoff,
    int* __restrict__ row_ptr, int* __restrict__ cursor, int N) {
    __shared__ int red[SCAN_BLOCK];
    int b = blockIdx.x, t = threadIdx.x;
    int base = b * SCAN_TILE + t * SCAN_ITEMS;
    int v[SCAN_ITEMS];
    int s = 0;
#pragma unroll
    for (int j = 0; j < SCAN_ITEMS; j++) {
        int i = base + j;
        v[j] = (i < N) ? deg[i] : 0;
        s += v[j];
    }
    red[t] = s;
    __syncthreads();
    for (int off = 1; off < SCAN_BLOCK; off <<= 1) {
        int x = (t >= off) ? red[t - off] : 0;
        __syncthreads();
        red[t] += x;
        __syncthreads();
    }
    int run = blockoff[b] + ((t == 0) ? 0 : red[t - 1]);
#pragma unroll
    for (int j = 0; j < SCAN_ITEMS; j++) {
        int i = base + j;
        if (i < N) { row_ptr[i] = run; cursor[i] = run; run += v[j]; }
    }
}
// -------------------------------------------------------------------------------

// a0 = concat(user_embed, entity_embed), contiguous N x 64
__global__ void build_a0(const float4* __restrict__ ue, const float4* __restrict__ ee,
                         float4* __restrict__ a0, int nu4, int ntot4) {
    int i = blockIdx.x * blockDim.x + threadIdx.x;
    if (i < ntot4) a0[i] = (i < nu4) ? ue[i] : ee[i - nu4];
}

// CSR packed as int2 {col, float_bits(val)} -> one 8B load per edge
__global__ void fill_csr(const int* __restrict__ row, const int* __restrict__ col,
                         const float* __restrict__ val, int E,
                         int* __restrict__ cursor, int2* __restrict__ csr) {
    int i = blockIdx.x * blockDim.x + threadIdx.x;
    if (i < E) {
        int r = row[i];
        int p = atomicAdd(&cursor[r], 1);
        csr[p] = make_int2(col[i], __float_as_int(val[i]));
    }
}

// Fused GNN layer: one wave per node (lane = dim). CSR gather-aggregate ->
// bilinear MLP -> leaky_relu -> L2 normalize.
template<int DOUT>
__global__ __launch_bounds__(512) void gnn_layer(
    const float* __restrict__ feats, const int2* __restrict__ csr,
    const int* __restrict__ row_ptr,
    const float* __restrict__ W1, const float* __restrict__ b1,
    const float* __restrict__ W2, const float* __restrict__ b2,
    float* __restrict__ out, int N) {
    __shared__ __align__(16) float w1t[DOUT * 68];
    __shared__ __align__(16) float w2t[DOUT * 68];
    __shared__ __align__(16) float s12[8][128];
    for (int idx = threadIdx.x; idx < 64 * DOUT; idx += 512) {
        int k = idx / DOUT, d = idx % DOUT;   // W[k][d], k-major in global
        w1t[d * 68 + k] = W1[idx];
        w2t[d * 68 + k] = W2[idx];
    }
    __syncthreads();
    int wv = threadIdx.x >> 6, lane = threadIdx.x & 63;
    int node = blockIdx.x * 8 + wv;
    if (node >= N) return;
    float x = feats[(size_t)node * 64 + lane];
    int e0 = row_ptr[node], e1 = row_ptr[node + 1];
    float acc = 0.f;
    int e = e0;
    for (; e + 4 <= e1; e += 4) {
        int2 p0 = csr[e], p1 = csr[e + 1], p2 = csr[e + 2], p3 = csr[e + 3];
        float f0 = feats[(size_t)p0.x * 64 + lane];
        float f1 = feats[(size_t)p1.x * 64 + lane];
        float f2 = feats[(size_t)p2.x * 64 + lane];
        float f3 = feats[(size_t)p3.x * 64 + lane];
        acc = fmaf(__int_as_float(p0.y), f0, acc);
        acc = fmaf(__int_as_float(p1.y), f1, acc);
        acc = fmaf(__int_as_float(p2.y), f2, acc);
        acc = fmaf(__int_as_float(p3.y), f3, acc);
    }
    for (; e < e1; e++) {
        int2 p = csr[e];
        acc = fmaf(__int_as_float(p.y), feats[(size_t)p.x * 64 + lane], acc);
    }
    float* sp = s12[wv];
    *(float2*)&sp[lane * 2] = make_float2(x + acc, x * acc);  // s1, s2 interleaved
    __threadfence_block();
    int d = lane % DOUT;
    float o = b1[d] + b2[d];
    const float* w1p = &w1t[d * 68];
    const float* w2p = &w2t[d * 68];
#pragma unroll
    for (int k = 0; k < 64; k += 4) {
        float4 sa = *(const float4*)&sp[2 * k];
        float4 sb = *(const float4*)&sp[2 * k + 4];
        float4 wa = *(const float4*)&w1p[k];
        float4 wb = *(const float4*)&w2p[k];
        o = fmaf(sa.x, wa.x, o);
        o = fmaf(sa.y, wb.x, o);
        o = fmaf(sa.z, wa.y, o);
        o = fmaf(sa.w, wb.y, o);
        o = fmaf(sb.x, wa.z, o);
        o = fmaf(sb.y, wb.z, o);
        o = fmaf(sb.z, wa.w, o);
        o = fmaf(sb.w, wb.w, o);
    }
    float h = (o > 0.f) ? o : LEAKY * o;
    float hh = (lane < DOUT) ? h : 0.f;
    float ss = hh * hh;
#pragma unroll
    for (int m = 32; m >= 1; m >>= 1) ss += __shfl_xor(ss, m, 64);
    float scale = 1.0f / fmaxf(sqrtf(ss), 1e-12f);
    if (lane < DOUT) out[(size_t)node * DOUT + lane] = h * scale;
}

// final = concat(a0, a1, a2); score[b] = dot(final[u], final[NU+i]) over 160 dims
__global__ __launch_bounds__(256) void score_pairs(
    const float* __restrict__ a0, const float* __restrict__ a1,
    const float* __restrict__ a2,
    const int* __restrict__ uid, const int* __restrict__ iid,
    float* __restrict__ out, int B, int NU) {
    int wave = threadIdx.x >> 6, lane = threadIdx.x & 63;
    int p = blockIdx.x * 4 + wave;
    if (p >= B) return;
    int u = uid[p], it = iid[p];
    size_t un = (size_t)u, in = (size_t)(NU + it);
    float s = a0[un * 64 + lane] * a0[in * 64 + lane];
    s = fmaf(a1[un * 64 + lane], a1[in * 64 + lane], s);
    if (lane < 32) s = fmaf(a2[un * 32 + lane], a2[in * 32 + lane], s);
#pragma unroll
    for (int m = 32; m >= 1; m >>= 1) s += __shfl_xor(s, m, 64);
    if (lane == 0) out[p] = s;
}

extern "C" void kernel_launch(void* const* d_in, const int* in_sizes, int n_in,
                              void* d_out, int out_size, void* d_ws, size_t ws_size,
                              hipStream_t stream) {
    const int*   edge_row  = (const int*)d_in[0];
    const int*   edge_col  = (const int*)d_in[1];
    const float* edge_vals = (const float*)d_in[2];
    const float* ue        = (const float*)d_in[3];
    const float* ee        = (const float*)d_in[4];
    const float* W1_0 = (const float*)d_in[5];
    const float* b1_0 = (const float*)d_in[6];
    const float* W2_0 = (const float*)d_in[7];
    const float* b2_0 = (const float*)d_in[8];
    const float* W1_1 = (const float*)d_in[9];
    const float* b1_1 = (const float*)d_in[10];
    const float* W2_1 = (const float*)d_in[11];
    const float* b2_1 = (const float*)d_in[12];
    const int*   uid  = (const int*)d_in[13];
    const int*   iid  = (const int*)d_in[14];
    float* out = (float*)d_out;

    const int E  = in_sizes[0];
    const int NU = in_sizes[3] / 64;
    const int NE = in_sizes[4] / 64;
    const int N  = NU + NE;
    const int B  = in_sizes[13];
    const int G  = (N + SCAN_TILE - 1) / SCAN_TILE;

    char* ws = (char*)d_ws;
    size_t off = 0;
    auto alloc = [&](size_t bytes) -> char* {
        char* p = ws + off;
        off = (off + bytes + 255) & ~(size_t)255;
        return p;
    };
    int*   deg      = (int*)alloc((size_t)N * 4);
    int*   row_ptr  = (int*)alloc((size_t)(N + 1) * 4);
    int*   cursor   = (int*)alloc((size_t)N * 4);
    int*   blocksum = (int*)alloc((size_t)1024 * 4);
    int*   blockoff = (int*)alloc((size_t)1024 * 4);
    int2*  csr      = (int2*)alloc((size_t)E * 8);
    float* a0       = (float*)alloc((size_t)N * 64 * 4);
    float* a1       = (float*)alloc((size_t)N * 64 * 4);
    float* a2       = (float*)alloc((size_t)N * 32 * 4);
    (void)ws_size; (void)n_in; (void)out_size; (void)NE;

    zero_i32<<<(N + 255) / 256, 256, 0, stream>>>(deg, N);
    count_edges<<<(E + 255) / 256, 256, 0, stream>>>(edge_row, E, deg);
    scan_phase1<<<G, SCAN_BLOCK, 0, stream>>>(deg, blocksum, N);
    scan_phase2<<<1, 1024, 0, stream>>>(blocksum, blockoff, row_ptr, G, N);
    scan_phase3<<<G, SCAN_BLOCK, 0, stream>>>(deg, blockoff, row_ptr, cursor, N);
    fill_csr<<<(E + 255) / 256, 256, 0, stream>>>(edge_row, edge_col, edge_vals, E,
                                                  cursor, csr);
    int ntot4 = N * 16, nu4 = NU * 16;
    build_a0<<<(ntot4 + 255) / 256, 256, 0, stream>>>((const float4*)ue, (const float4*)ee,
                                                      (float4*)a0, nu4, ntot4);
    gnn_layer<64><<<(N + 7) / 8, 512, 0, stream>>>(a0, csr, row_ptr,
                                                   W1_0, b1_0, W2_0, b2_0, a1, N);
    gnn_layer<32><<<(N + 7) / 8, 512, 0, stream>>>(a1, csr, row_ptr,
                                                   W1_1, b1_1, W2_1, b2_1, a2, N);
    score_pairs<<<(B + 3) / 4, 256, 0, stream>>>(a0, a1, a2, uid, iid, out, B, NU);
}